// Round 3
// baseline (170.962 us; speedup 1.0000x reference)
//
#include <hip/hip_runtime.h>
#include <math.h>

#define NB 256
#define NT 64
#define DIN 512
#define DSAE 4096
#define NK 32

// ---------------- pe column sums + out[0] zero ----------------
__global__ void k_pesum(float* __restrict__ pesum, float* __restrict__ out) {
    int d = threadIdx.x;              // 512 threads, 1 block
    if (d == 0) out[0] = 0.f;         // loss accumulator zero (k_dec atomicAdds later)
    int j = d >> 1;
    float freq = expf((float)(2 * j) * (-9.210340371976184f / 512.0f)); // exp(-2j*ln(1e4)/512)
    float s = 0.f;
    if (d & 1) {
        for (int t = 0; t < NT; ++t) s += cosf((float)t * freq);
    } else {
        for (int t = 0; t < NT; ++t) s += sinf((float)t * freq);
    }
    pesum[d] = s;
}

// ---------------- xs[b,d] = sum_t x[b,t,d] + pesum[d] ----------------
__global__ void k_xs(const float* __restrict__ x, const float* __restrict__ pesum,
                     float* __restrict__ xs) {
    int b = blockIdx.x, d = threadIdx.x;   // grid NB, block 512
    const float* xp = x + (size_t)b * NT * DIN + d;
    float acc = 0.f;
#pragma unroll 16
    for (int t = 0; t < NT; ++t) acc += xp[(size_t)t * DIN];
    xs[(size_t)b * DIN + d] = acc + pesum[d];
}

// ---------------- pre = xs @ W_enc + b_enc  (256x512 · 512x4096) ----------------
__global__ __launch_bounds__(256) void k_pre(const float* __restrict__ xs,
                                             const float* __restrict__ W,
                                             const float* __restrict__ b_enc,
                                             float* __restrict__ pre) {
    __shared__ float xs_t[DIN][8];   // transposed tile: [d][bb], 16 KB
    const int tid = threadIdx.x;
    const int s = blockIdx.x * 256 + tid;
    const int b0 = blockIdx.y * 8;
    for (int i = tid; i < 8 * DIN; i += 256) {
        int bb = i >> 9, d = i & 511;
        xs_t[d][bb] = xs[(size_t)(b0 + bb) * DIN + d];
    }
    __syncthreads();
    // dual accumulators (even/odd d) for accuracy near the top-k rank boundary
    float a0=0,a1=0,a2=0,a3=0,a4=0,a5=0,a6=0,a7=0;
    float c0=0,c1=0,c2=0,c3=0,c4=0,c5=0,c6=0,c7=0;
    const float* wp = W + s;
#pragma unroll 4
    for (int d = 0; d < DIN; d += 2) {
        float w0 = wp[(size_t)d * DSAE];
        float w1 = wp[(size_t)(d + 1) * DSAE];
        float4 lo0 = *(const float4*)&xs_t[d][0];
        float4 hi0 = *(const float4*)&xs_t[d][4];
        float4 lo1 = *(const float4*)&xs_t[d + 1][0];
        float4 hi1 = *(const float4*)&xs_t[d + 1][4];
        a0 += lo0.x * w0; a1 += lo0.y * w0; a2 += lo0.z * w0; a3 += lo0.w * w0;
        a4 += hi0.x * w0; a5 += hi0.y * w0; a6 += hi0.z * w0; a7 += hi0.w * w0;
        c0 += lo1.x * w1; c1 += lo1.y * w1; c2 += lo1.z * w1; c3 += lo1.w * w1;
        c4 += hi1.x * w1; c5 += hi1.y * w1; c6 += hi1.z * w1; c7 += hi1.w * w1;
    }
    float be = b_enc[s];
    pre[(size_t)(b0 + 0) * DSAE + s] = a0 + c0 + be;
    pre[(size_t)(b0 + 1) * DSAE + s] = a1 + c1 + be;
    pre[(size_t)(b0 + 2) * DSAE + s] = a2 + c2 + be;
    pre[(size_t)(b0 + 3) * DSAE + s] = a3 + c3 + be;
    pre[(size_t)(b0 + 4) * DSAE + s] = a4 + c4 + be;
    pre[(size_t)(b0 + 5) * DSAE + s] = a5 + c5 + be;
    pre[(size_t)(b0 + 6) * DSAE + s] = a6 + c6 + be;
    pre[(size_t)(b0 + 7) * DSAE + s] = a7 + c7 + be;
}

// ---------------- top-32 per row, fused z-row zero, index-sorted output ----------------
__global__ __launch_bounds__(256) void k_topk(const float* __restrict__ pre,
                                              float* __restrict__ z_out,
                                              int* __restrict__ idx_s,
                                              float* __restrict__ zv_s) {
    int b = blockIdx.x, tid = threadIdx.x;
    float* zr = z_out + (size_t)b * DSAE;        // 4B-aligned only -> scalar stores
    for (int j = tid; j < DSAE; j += 256) zr[j] = 0.f;
    float v[16];
#pragma unroll
    for (int j = 0; j < 16; ++j) v[j] = pre[(size_t)b * DSAE + tid + j * 256];
    __shared__ float s_val[4];
    __shared__ int s_idx[4];
    __shared__ int s_gi;
    __shared__ int all_i[NK];
    __shared__ float all_v[NK];
    for (int k = 0; k < NK; ++k) {
        float bv = -INFINITY; int bi = 0x7fffffff;
#pragma unroll
        for (int j = 0; j < 16; ++j) {
            int ei = tid + j * 256;
            if (v[j] > bv || (v[j] == bv && ei < bi)) { bv = v[j]; bi = ei; }
        }
#pragma unroll
        for (int off = 32; off >= 1; off >>= 1) {
            float ov = __shfl_down(bv, off);
            int oi = __shfl_down(bi, off);
            if (ov > bv || (ov == bv && oi < bi)) { bv = ov; bi = oi; }
        }
        if ((tid & 63) == 0) { s_val[tid >> 6] = bv; s_idx[tid >> 6] = bi; }
        __syncthreads();
        if (tid == 0) {
            float gv = s_val[0]; int gi = s_idx[0];
            for (int w = 1; w < 4; ++w) {
                if (s_val[w] > gv || (s_val[w] == gv && s_idx[w] < gi)) {
                    gv = s_val[w]; gi = s_idx[w];
                }
            }
            s_gi = gi;
            float r = gv > 0.f ? gv : 0.f;
            all_i[k] = gi;
            all_v[k] = r;
            zr[gi] = r;
        }
        __syncthreads();
        int gi = s_gi;
#pragma unroll
        for (int j = 0; j < 16; ++j)
            if (tid + j * 256 == gi) v[j] = -INFINITY;
    }
    // rank-sort the 32 (idx,val) pairs by ascending index (indices are distinct)
    if (tid < NK) {
        int myi = all_i[tid]; float myv = all_v[tid];
        int rank = 0;
#pragma unroll
        for (int j = 0; j < NK; ++j) rank += (all_i[j] < myi) ? 1 : 0;
        idx_s[b * NK + rank] = myi;
        zv_s[b * NK + rank] = myv;
    }
}

// ---------------- decoder: ONE BLOCK PER BATCH for lockstep L3 banding ----------------
// grid NB, block 1024 (16 waves, 1 block/CU, all 256 blocks co-resident in one
// generation). Sorted indices -> at iteration k every block reads rows near rank
// k*4096/33 (±2sigma ~ 175 MB < 256 MB L3), so duplicate rows across batches hit L3.
__global__ __launch_bounds__(1024, 4) void k_dec(const float* __restrict__ x,
                                                 const float* __restrict__ Wd,
                                                 const float* __restrict__ bd,
                                                 const int* __restrict__ idx_s,
                                                 const float* __restrict__ zv_s,
                                                 float* __restrict__ out) {
    const int b = blockIdx.x, tid = threadIdx.x;
    __shared__ int si[NK];
    __shared__ float sz[NK];
    if (tid < NK) { si[tid] = idx_s[b * NK + tid]; sz[tid] = zv_s[b * NK + tid]; }
    __syncthreads();
    const float4* bd4 = (const float4*)bd;
    float4 acc[8];
#pragma unroll
    for (int q = 0; q < 8; ++q) acc[q] = bd4[tid + q * 1024];
    for (int k = 0; k < NK; ++k) {
        const float4* w4 = (const float4*)(Wd + (size_t)si[k] * (NT * DIN));
        float zk = sz[k];
#pragma unroll
        for (int q = 0; q < 8; ++q) {
            float4 w = w4[tid + q * 1024];
            acc[q].x += zk * w.x; acc[q].y += zk * w.y;
            acc[q].z += zk * w.z; acc[q].w += zk * w.w;
        }
    }
    // x is single-use: nontemporal loads keep the L3 for the W_dec band
    const float* xr = x + (size_t)b * (NT * DIN);
    float* xh = out + 1 + (size_t)b * (NT * DIN);   // 4B-aligned only -> scalar stores
    float lsum = 0.f;
#pragma unroll
    for (int q = 0; q < 8; ++q) {
        int e = (tid + q * 1024) * 4;
        float x0 = __builtin_nontemporal_load(&xr[e]);
        float x1 = __builtin_nontemporal_load(&xr[e + 1]);
        float x2 = __builtin_nontemporal_load(&xr[e + 2]);
        float x3 = __builtin_nontemporal_load(&xr[e + 3]);
        float d0 = acc[q].x - x0, d1 = acc[q].y - x1;
        float d2 = acc[q].z - x2, d3 = acc[q].w - x3;
        lsum += d0 * d0 + d1 * d1 + d2 * d2 + d3 * d3;
        __builtin_nontemporal_store(acc[q].x, &xh[e]);
        __builtin_nontemporal_store(acc[q].y, &xh[e + 1]);
        __builtin_nontemporal_store(acc[q].z, &xh[e + 2]);
        __builtin_nontemporal_store(acc[q].w, &xh[e + 3]);
    }
    // block-reduce loss partial (16 waves)
#pragma unroll
    for (int off = 32; off >= 1; off >>= 1) lsum += __shfl_down(lsum, off);
    __shared__ float red[16];
    if ((tid & 63) == 0) red[tid >> 6] = lsum;
    __syncthreads();
    if (tid == 0) {
        float tot = 0.f;
#pragma unroll
        for (int w = 0; w < 16; ++w) tot += red[w];
        atomicAdd(out, tot * (1.0f / (NB * NT)));
    }
}

extern "C" void kernel_launch(void* const* d_in, const int* in_sizes, int n_in,
                              void* d_out, int out_size, void* d_ws, size_t ws_size,
                              hipStream_t stream) {
    const float* x     = (const float*)d_in[0];
    const float* W_enc = (const float*)d_in[1];
    const float* W_dec = (const float*)d_in[2];
    const float* b_enc = (const float*)d_in[3];
    const float* b_dec = (const float*)d_in[4];
    float* out = (float*)d_out;

    float* ws    = (float*)d_ws;
    float* pesum = ws;                      // 512
    float* xs    = ws + 512;                // 256*512   = 131072
    float* pre   = ws + 131584;             // 256*4096  = 1048576
    int*   idx_s = (int*)(ws + 1180160);    // 256*32 sorted indices
    float* zv_s  = ws + 1188352;            // 256*32 sorted values

    float* z_out = out + 1 + (size_t)NB * NT * DIN;  // z region

    k_pesum<<<1, 512, 0, stream>>>(pesum, out);
    k_xs<<<NB, 512, 0, stream>>>(x, pesum, xs);
    k_pre<<<dim3(16, 32), 256, 0, stream>>>(xs, W_enc, b_enc, pre);
    k_topk<<<NB, 256, 0, stream>>>(pre, z_out, idx_s, zv_s);
    k_dec<<<NB, 1024, 0, stream>>>(x, W_dec, b_dec, idx_s, zv_s, out);
}

// Round 4
// 156.243 us; speedup vs baseline: 1.0942x; 1.0942x over previous
//
#include <hip/hip_runtime.h>
#include <math.h>

#define NB 256
#define NT 64
#define DIN 512
#define DSAE 4096
#define NK 32

// ---------------- xs[b,d] = sum_t x[b,t,d] + pesum[d]  (pesum recomputed per block) ----------------
__global__ __launch_bounds__(512) void k_xs(const float* __restrict__ x,
                                            float* __restrict__ xs,
                                            float* __restrict__ out) {
    const int b = blockIdx.x, d = threadIdx.x;   // grid NB, block 512
    if (b == 0 && d == 0) out[0] = 0.f;          // loss accumulator zero (k_dec atomicAdds later)
    // per-thread pe column sum (identical formula to the old k_pesum)
    int j = d >> 1;
    float freq = expf((float)(2 * j) * (-9.210340371976184f / 512.0f));
    float pes = 0.f;
    if (d & 1) {
        for (int t = 0; t < NT; ++t) pes += cosf((float)t * freq);
    } else {
        for (int t = 0; t < NT; ++t) pes += sinf((float)t * freq);
    }
    const float* xp = x + (size_t)b * NT * DIN + d;
    float acc = 0.f;
#pragma unroll 16
    for (int t = 0; t < NT; ++t) acc += xp[(size_t)t * DIN];
    xs[(size_t)b * DIN + d] = acc + pes;
}

// ---------------- pre = xs @ W_enc + b_enc  (256x512 · 512x4096) ----------------
// grid (16 s-tiles, 16 b-tiles) = 256 blocks -> 1 block/CU, 1 wave/SIMD.
__global__ __launch_bounds__(256) void k_pre(const float* __restrict__ xs,
                                             const float* __restrict__ W,
                                             const float* __restrict__ b_enc,
                                             float* __restrict__ pre) {
    __shared__ float xs_t[DIN][16];   // transposed tile: [d][bb], 32 KB
    const int tid = threadIdx.x;
    const int s = blockIdx.x * 256 + tid;
    const int b0 = blockIdx.y * 16;
    for (int i = tid; i < 16 * DIN; i += 256) {
        int bb = i >> 9, d = i & 511;
        xs_t[d][bb] = xs[(size_t)(b0 + bb) * DIN + d];
    }
    __syncthreads();
    // dual accumulators (even/odd d) — same per-(d,batch) arithmetic order as before
    float a[16], c[16];
#pragma unroll
    for (int i = 0; i < 16; ++i) { a[i] = 0.f; c[i] = 0.f; }
    const float* wp = W + s;
#pragma unroll 2
    for (int d = 0; d < DIN; d += 2) {
        float w0 = wp[(size_t)d * DSAE];
        float w1 = wp[(size_t)(d + 1) * DSAE];
        const float4* r0 = (const float4*)&xs_t[d][0];
        const float4* r1 = (const float4*)&xs_t[d + 1][0];
#pragma unroll
        for (int q = 0; q < 4; ++q) {
            float4 u = r0[q];
            a[q*4+0] += u.x * w0; a[q*4+1] += u.y * w0;
            a[q*4+2] += u.z * w0; a[q*4+3] += u.w * w0;
            float4 t2 = r1[q];
            c[q*4+0] += t2.x * w1; c[q*4+1] += t2.y * w1;
            c[q*4+2] += t2.z * w1; c[q*4+3] += t2.w * w1;
        }
    }
    float be = b_enc[s];
#pragma unroll
    for (int bb = 0; bb < 16; ++bb)
        pre[(size_t)(b0 + bb) * DSAE + s] = a[bb] + c[bb] + be;
}

// ---------------- top-32 per row: 1 wave/batch, hierarchical incremental argmax ----------------
// Element e = slot j*64 + lane. Strict-> scans + lowest-e tiebreak == jax top_k semantics.
__global__ __launch_bounds__(64) void k_topk(const float* __restrict__ pre,
                                             float* __restrict__ z_out,
                                             int* __restrict__ idx_s,
                                             float* __restrict__ zv_s) {
    const int b = blockIdx.x, lane = threadIdx.x;
    const float* pr = pre + (size_t)b * DSAE;
    float* zr = z_out + (size_t)b * DSAE;
    __shared__ float lv[64 * 65];    // per-lane 64-value stash, pad 65 -> conflict-free init
    __shared__ float lgv[64 * 8];    // per-lane group maxima (8 groups of 8)
    __shared__ int   lga[64 * 8];
    // zero z row (drained by the __syncthreads below, before the final scatter)
    for (int j = lane; j < DSAE; j += 64) zr[j] = 0.f;
    const int base = lane * 65;
    float v[64];
#pragma unroll
    for (int j = 0; j < 64; ++j) v[j] = pr[j * 64 + lane];
#pragma unroll
    for (int j = 0; j < 64; ++j) lv[base + j] = v[j];
    float lmax = -INFINITY; int larg = 0;
#pragma unroll
    for (int g = 0; g < 8; ++g) {
        float m = v[g * 8]; int a = g * 8;
#pragma unroll
        for (int t = 1; t < 8; ++t)
            if (v[g * 8 + t] > m) { m = v[g * 8 + t]; a = g * 8 + t; }
        lgv[lane * 8 + g] = m; lga[lane * 8 + g] = a;
        if (m > lmax) { lmax = m; larg = a; }
    }
    __syncthreads();
    int myi = 0; float myv = 0.f;
    for (int k = 0; k < NK; ++k) {
        float bv = lmax; int be = larg * 64 + lane;
#pragma unroll
        for (int off = 32; off >= 1; off >>= 1) {
            float ov = __shfl_down(bv, off);
            int oe = __shfl_down(be, off);
            if (ov > bv || (ov == bv && oe < be)) { bv = ov; be = oe; }
        }
        bv = __shfl(bv, 0); be = __shfl(be, 0);
        if (lane == k) { myi = be; myv = bv > 0.f ? bv : 0.f; }
        if (lane == (be & 63)) {               // owner: remove element, rebuild group + local best
            int j0 = be >> 6;
            lv[base + j0] = -INFINITY;
            int g0 = j0 >> 3;
            float m = -INFINITY; int a2 = g0 << 3;
            for (int t = 0; t < 8; ++t) {
                float x2 = lv[base + (g0 << 3) + t];
                if (x2 > m) { m = x2; a2 = (g0 << 3) + t; }
            }
            lgv[lane * 8 + g0] = m; lga[lane * 8 + g0] = a2;
            lmax = -INFINITY; larg = 0;
            for (int g = 0; g < 8; ++g) {
                float x2 = lgv[lane * 8 + g];
                if (x2 > lmax) { lmax = x2; larg = lga[lane * 8 + g]; }
            }
        }
    }
    // rank-sort the 32 (idx,val) pairs by ascending index (indices distinct)
    int rank = 0;
#pragma unroll
    for (int j = 0; j < NK; ++j) {
        int oi = __shfl(myi, j);
        if (lane < NK && oi < myi) rank++;
    }
    if (lane < NK) {
        idx_s[b * NK + rank] = myi;
        zv_s[b * NK + rank] = myv;
        zr[myi] = myv;                 // ordered after zeroing via the earlier __syncthreads
    }
}

// ---------------- decoder: x_hat = sum_k zv_k * W_dec[i_k] + b_dec ; fused loss ----------------
// EXACT R2 version (best so far) for clean attribution.
__global__ __launch_bounds__(256) void k_dec(const float* __restrict__ x,
                                             const float* __restrict__ Wd,
                                             const float* __restrict__ bd,
                                             const int* __restrict__ idx_s,
                                             const float* __restrict__ zv_s,
                                             float* __restrict__ out) {
    const int b = blockIdx.y, chunk = blockIdx.x, tid = threadIdx.x;
    __shared__ int si[NK];
    __shared__ float sz[NK];
    if (tid < NK) { si[tid] = idx_s[b * NK + tid]; sz[tid] = zv_s[b * NK + tid]; }
    __syncthreads();
    const int f0 = chunk * 1024 + tid;            // float4 index within 32768-float row
    const float4* bd4 = (const float4*)bd;
    float4 acc0 = bd4[f0];
    float4 acc1 = bd4[f0 + 256];
    float4 acc2 = bd4[f0 + 512];
    float4 acc3 = bd4[f0 + 768];
    for (int k = 0; k < NK; ++k) {
        const float4* w4 = (const float4*)(Wd + (size_t)si[k] * (NT * DIN));
        float zk = sz[k];
        float4 w0 = w4[f0], w1 = w4[f0 + 256], w2 = w4[f0 + 512], w3 = w4[f0 + 768];
        acc0.x += zk * w0.x; acc0.y += zk * w0.y; acc0.z += zk * w0.z; acc0.w += zk * w0.w;
        acc1.x += zk * w1.x; acc1.y += zk * w1.y; acc1.z += zk * w1.z; acc1.w += zk * w1.w;
        acc2.x += zk * w2.x; acc2.y += zk * w2.y; acc2.z += zk * w2.z; acc2.w += zk * w2.w;
        acc3.x += zk * w3.x; acc3.y += zk * w3.y; acc3.z += zk * w3.z; acc3.w += zk * w3.w;
    }
    const float* xr = x + (size_t)b * (NT * DIN);
    float lsum = 0.f, dx;
    float xv[16];
#pragma unroll
    for (int q = 0; q < 4; ++q) {
        int e = (f0 + q * 256) * 4;
#pragma unroll
        for (int c2 = 0; c2 < 4; ++c2) xv[q * 4 + c2] = __builtin_nontemporal_load(&xr[e + c2]);
    }
    dx = acc0.x - xv[0];  lsum += dx * dx;  dx = acc0.y - xv[1];  lsum += dx * dx;
    dx = acc0.z - xv[2];  lsum += dx * dx;  dx = acc0.w - xv[3];  lsum += dx * dx;
    dx = acc1.x - xv[4];  lsum += dx * dx;  dx = acc1.y - xv[5];  lsum += dx * dx;
    dx = acc1.z - xv[6];  lsum += dx * dx;  dx = acc1.w - xv[7];  lsum += dx * dx;
    dx = acc2.x - xv[8];  lsum += dx * dx;  dx = acc2.y - xv[9];  lsum += dx * dx;
    dx = acc2.z - xv[10]; lsum += dx * dx;  dx = acc2.w - xv[11]; lsum += dx * dx;
    dx = acc3.x - xv[12]; lsum += dx * dx;  dx = acc3.y - xv[13]; lsum += dx * dx;
    dx = acc3.z - xv[14]; lsum += dx * dx;  dx = acc3.w - xv[15]; lsum += dx * dx;

    float* xh = out + 1 + (size_t)b * (NT * DIN);   // 4B-aligned only -> scalar stores
    int e;
    e = f0 * 4;
    __builtin_nontemporal_store(acc0.x, &xh[e]);     __builtin_nontemporal_store(acc0.y, &xh[e+1]);
    __builtin_nontemporal_store(acc0.z, &xh[e+2]);   __builtin_nontemporal_store(acc0.w, &xh[e+3]);
    e = (f0 + 256) * 4;
    __builtin_nontemporal_store(acc1.x, &xh[e]);     __builtin_nontemporal_store(acc1.y, &xh[e+1]);
    __builtin_nontemporal_store(acc1.z, &xh[e+2]);   __builtin_nontemporal_store(acc1.w, &xh[e+3]);
    e = (f0 + 512) * 4;
    __builtin_nontemporal_store(acc2.x, &xh[e]);     __builtin_nontemporal_store(acc2.y, &xh[e+1]);
    __builtin_nontemporal_store(acc2.z, &xh[e+2]);   __builtin_nontemporal_store(acc2.w, &xh[e+3]);
    e = (f0 + 768) * 4;
    __builtin_nontemporal_store(acc3.x, &xh[e]);     __builtin_nontemporal_store(acc3.y, &xh[e+1]);
    __builtin_nontemporal_store(acc3.z, &xh[e+2]);   __builtin_nontemporal_store(acc3.w, &xh[e+3]);

#pragma unroll
    for (int off = 32; off >= 1; off >>= 1) lsum += __shfl_down(lsum, off);
    __shared__ float red[4];
    if ((tid & 63) == 0) red[tid >> 6] = lsum;
    __syncthreads();
    if (tid == 0) {
        float tot = red[0] + red[1] + red[2] + red[3];
        atomicAdd(out, tot * (1.0f / (NB * NT)));
    }
}

extern "C" void kernel_launch(void* const* d_in, const int* in_sizes, int n_in,
                              void* d_out, int out_size, void* d_ws, size_t ws_size,
                              hipStream_t stream) {
    const float* x     = (const float*)d_in[0];
    const float* W_enc = (const float*)d_in[1];
    const float* W_dec = (const float*)d_in[2];
    const float* b_enc = (const float*)d_in[3];
    const float* b_dec = (const float*)d_in[4];
    float* out = (float*)d_out;

    float* ws    = (float*)d_ws;
    float* xs    = ws;                        // 256*512   = 131072
    float* pre   = ws + 131072;               // 256*4096  = 1048576
    int*   idx_s = (int*)(ws + 1179648);      // 256*32 sorted indices
    float* zv_s  = ws + 1187840;              // 256*32 sorted values

    float* z_out = out + 1 + (size_t)NB * NT * DIN;  // z region

    k_xs<<<NB, 512, 0, stream>>>(x, xs, out);
    k_pre<<<dim3(16, 16), 256, 0, stream>>>(xs, W_enc, b_enc, pre);
    k_topk<<<NB, 64, 0, stream>>>(pre, z_out, idx_s, zv_s);
    k_dec<<<dim3(8, NB), 256, 0, stream>>>(x, W_dec, b_dec, idx_s, zv_s, out);
}